// Round 1
// baseline (184.564 us; speedup 1.0000x reference)
//
#include <hip/hip_runtime.h>
#include <hip/hip_bf16.h>
#include <float.h>

#define SDIM 192
#define S2 (SDIM*SDIM)        // 36864
#define S3 (SDIM*S2)          // 7077888
#define NCH 5
#define RAD 4                 // window 9
#define DCHUNK 48             // K3 d-chunk
#define POSBLK 144            // 36864 / 256
#define NPART (POSBLK * (SDIM/DCHUNK))   // 576

// ---- storage-type helpers (float or bf16 workspace) ----
template <typename T> __device__ __forceinline__ float toF(T x);
template <> __device__ __forceinline__ float toF<float>(float x) { return x; }
template <> __device__ __forceinline__ float toF<__hip_bfloat16>(__hip_bfloat16 x) { return __bfloat162float(x); }

template <typename T> __device__ __forceinline__ T fromF(float x);
template <> __device__ __forceinline__ float fromF<float>(float x) { return x; }
template <> __device__ __forceinline__ __hip_bfloat16 fromF<__hip_bfloat16>(float x) { return __float2bfloat16(x); }

// ---------------- K1: W-axis 9-tap zero-padded sum of the 5 product channels ----------------
template <typename AT>
__global__ __launch_bounds__(SDIM) void k1_wfilter(const float* __restrict__ pred,
                                                   const float* __restrict__ tgt,
                                                   AT* __restrict__ A) {
    const int row = blockIdx.x;            // (d*192 + h), 0..36863
    const int w = threadIdx.x;             // 0..191
    __shared__ float Ir[SDIM];
    __shared__ float Jr[SDIM];
    const size_t base = (size_t)row * SDIM;
    Ir[w] = tgt[base + w];                 // I = target
    Jr[w] = pred[base + w];                // J = pred
    __syncthreads();

    float s0 = 0.f, s1 = 0.f, s2 = 0.f, s3 = 0.f, s4 = 0.f;
#pragma unroll
    for (int dw = -RAD; dw <= RAD; ++dw) {
        const int x = w + dw;
        if (x >= 0 && x < SDIM) {
            const float i = Ir[x];
            const float j = Jr[x];
            s0 += i; s1 += j; s2 += i * i; s3 += j * j; s4 += i * j;
        }
    }
    A[0 * (size_t)S3 + base + w] = fromF<AT>(s0);
    A[1 * (size_t)S3 + base + w] = fromF<AT>(s1);
    A[2 * (size_t)S3 + base + w] = fromF<AT>(s2);
    A[3 * (size_t)S3 + base + w] = fromF<AT>(s3);
    A[4 * (size_t)S3 + base + w] = fromF<AT>(s4);
}

// ---------------- K2: H-axis 9-tap sum, in place (block owns its region exclusively) ----------------
template <typename AT>
__global__ __launch_bounds__(256) void k2_hfilter(AT* __restrict__ A) {
    // blockIdx.x = c*(192*3) + d*3 + wc   ; wc selects a 64-wide W chunk
    const int b = blockIdx.x;
    const int wc = b % 3;
    const int d = (b / 3) % SDIM;
    const int c = b / (3 * SDIM);
    __shared__ float tile[SDIM][64];       // 48 KB

    const size_t base = (size_t)c * S3 + (size_t)d * S2 + (size_t)(wc * 64);
    const int t = threadIdx.x;

    for (int idx = t; idx < SDIM * 64; idx += 256) {
        const int h = idx >> 6;
        const int w = idx & 63;
        tile[h][w] = toF<AT>(A[base + (size_t)h * SDIM + w]);
    }
    __syncthreads();

    const int w = t & 63;
    const int h0 = t >> 6;                 // 0..3
    for (int h = h0; h < SDIM; h += 4) {
        float s = 0.f;
#pragma unroll
        for (int dh = -RAD; dh <= RAD; ++dh) {
            const int y = h + dh;
            if (y >= 0 && y < SDIM) s += tile[y][w];
        }
        A[base + (size_t)h * SDIM + w] = fromF<AT>(s);
    }
}

// ---------------- K3: D-axis running-window sum + cc + deterministic block reduction ----------------
template <typename AT>
__global__ __launch_bounds__(256) void k3_dfilter_cc(const AT* __restrict__ A,
                                                     float* __restrict__ partials) {
    const int bid = blockIdx.x;            // dc*POSBLK + pb
    const int dc = bid / POSBLK;
    const int pb = bid % POSBLK;
    const int pos = pb * 256 + threadIdx.x;   // (h*192 + w), 0..36863
    const int d0 = dc * DCHUNK;

    float z[NCH] = {0.f, 0.f, 0.f, 0.f, 0.f};
    // warm up: window sum for output d0 over d0-4..d0+4 (zero-padded)
#pragma unroll
    for (int dd = -RAD; dd <= RAD; ++dd) {
        const int d = d0 + dd;
        if (d >= 0 && d < SDIM) {
#pragma unroll
            for (int c = 0; c < NCH; ++c)
                z[c] += toF<AT>(A[(size_t)c * S3 + (size_t)d * S2 + pos]);
        }
    }

    const float inv = 1.0f / 729.0f;
    const float eps = 1.1920929e-07f;      // np.finfo(float32).eps
    float acc = 0.f;

    for (int d = d0; d < d0 + DCHUNK; ++d) {
        const float mu1 = z[0] * inv;
        const float mu2 = z[1] * inv;
        const float cI2 = z[2] * inv;
        const float cJ2 = z[3] * inv;
        const float cIJ = z[4] * inv;
        const float sg1 = cI2 - mu1 * mu1;
        const float sg2 = cJ2 - mu2 * mu2;
        const float s12 = cIJ - mu1 * mu2;
        acc += (s12 * s12) / (sg1 * sg2 + eps);

        // slide window: remove d-4, add d+5
        const int da = d + RAD + 1;
        const int ds = d - RAD;
        if (da < SDIM) {
#pragma unroll
            for (int c = 0; c < NCH; ++c)
                z[c] += toF<AT>(A[(size_t)c * S3 + (size_t)da * S2 + pos]);
        }
        if (ds >= 0) {
#pragma unroll
            for (int c = 0; c < NCH; ++c)
                z[c] -= toF<AT>(A[(size_t)c * S3 + (size_t)ds * S2 + pos]);
        }
    }

    __shared__ float red[256];
    red[threadIdx.x] = acc;
    __syncthreads();
#pragma unroll
    for (int o = 128; o > 0; o >>= 1) {
        if (threadIdx.x < o) red[threadIdx.x] += red[threadIdx.x + o];
        __syncthreads();
    }
    if (threadIdx.x == 0) partials[bid] = red[0];
}

// ---------------- K4: final deterministic reduction ----------------
__global__ __launch_bounds__(256) void k4_finalize(const float* __restrict__ partials,
                                                   float* __restrict__ out) {
    __shared__ float sm[256];
    float s = 0.f;
    for (int i = threadIdx.x; i < NPART; i += 256) s += partials[i];
    sm[threadIdx.x] = s;
    __syncthreads();
#pragma unroll
    for (int o = 128; o > 0; o >>= 1) {
        if (threadIdx.x < o) sm[threadIdx.x] += sm[threadIdx.x + o];
        __syncthreads();
    }
    if (threadIdx.x == 0) out[0] = 1.0f - sm[0] / (float)S3;
}

extern "C" void kernel_launch(void* const* d_in, const int* in_sizes, int n_in,
                              void* d_out, int out_size, void* d_ws, size_t ws_size,
                              hipStream_t stream) {
    const float* pred = (const float*)d_in[0];
    const float* tgt  = (const float*)d_in[1];
    float* out = (float*)d_out;

    const size_t a_f32 = (size_t)NCH * S3 * sizeof(float);      // ~141.6 MB
    const size_t a_f32_pad = (a_f32 + 255) & ~(size_t)255;
    const size_t a_bf  = (size_t)NCH * S3 * sizeof(__hip_bfloat16);
    const size_t a_bf_pad = (a_bf + 255) & ~(size_t)255;

    const bool use_f32 = ws_size >= a_f32_pad + NPART * sizeof(float);

    if (use_f32) {
        float* A = (float*)d_ws;
        float* partials = (float*)((char*)d_ws + a_f32_pad);
        k1_wfilter<float><<<S2, SDIM, 0, stream>>>(pred, tgt, A);
        k2_hfilter<float><<<NCH * SDIM * 3, 256, 0, stream>>>(A);
        k3_dfilter_cc<float><<<NPART, 256, 0, stream>>>(A, partials);
        k4_finalize<<<1, 256, 0, stream>>>(partials, out);
    } else {
        __hip_bfloat16* A = (__hip_bfloat16*)d_ws;
        float* partials = (float*)((char*)d_ws + a_bf_pad);
        k1_wfilter<__hip_bfloat16><<<S2, SDIM, 0, stream>>>(pred, tgt, A);
        k2_hfilter<__hip_bfloat16><<<NCH * SDIM * 3, 256, 0, stream>>>(A);
        k3_dfilter_cc<__hip_bfloat16><<<NPART, 256, 0, stream>>>(A, partials);
        k4_finalize<<<1, 256, 0, stream>>>(partials, out);
    }
}